// Round 1
// baseline (518.422 us; speedup 1.0000x reference)
//
#include <hip/hip_runtime.h>
#include <math.h>

// Problem constants
#define B8   8
#define G8   8
#define C4   1024
#define C5   2048
#define O4   512
#define O5   1024
#define HW4  196   // 14*14
#define HW5  49    // 7*7
#define HFW  28
#define NPIX 784   // 28*28
#define CAPP 1536
#define D1   38400 // 1536*25
#define NR   64    // B*G
#define DH   512

#define FMA16(S, W)  do { \
  float4 _a = (W)[0], _b = (W)[1], _c = (W)[2], _d = (W)[3]; \
  acc[0]  = fmaf((S), _a.x, acc[0]);  acc[1]  = fmaf((S), _a.y, acc[1]); \
  acc[2]  = fmaf((S), _a.z, acc[2]);  acc[3]  = fmaf((S), _a.w, acc[3]); \
  acc[4]  = fmaf((S), _b.x, acc[4]);  acc[5]  = fmaf((S), _b.y, acc[5]); \
  acc[6]  = fmaf((S), _b.z, acc[6]);  acc[7]  = fmaf((S), _b.w, acc[7]); \
  acc[8]  = fmaf((S), _c.x, acc[8]);  acc[9]  = fmaf((S), _c.y, acc[9]); \
  acc[10] = fmaf((S), _c.z, acc[10]); acc[11] = fmaf((S), _c.w, acc[11]); \
  acc[12] = fmaf((S), _d.x, acc[12]); acc[13] = fmaf((S), _d.y, acc[13]); \
  acc[14] = fmaf((S), _d.z, acc[14]); acc[15] = fmaf((S), _d.w, acc[15]); \
} while(0)

#define STORE16(P) do { \
  ((float4*)(P))[0] = make_float4(acc[0],acc[1],acc[2],acc[3]); \
  ((float4*)(P))[1] = make_float4(acc[4],acc[5],acc[6],acc[7]); \
  ((float4*)(P))[2] = make_float4(acc[8],acc[9],acc[10],acc[11]); \
  ((float4*)(P))[3] = make_float4(acc[12],acc[13],acc[14],acc[15]); \
} while(0)

// ---------------- conv1x1 on x4: f4pT[kz][b][hw][o] (transposed, K-split by 2) ----
__global__ __launch_bounds__(256) void conv4_kernel(
    const float* __restrict__ x4, const float* __restrict__ w2,
    float* __restrict__ f4p) {
  int b = blockIdx.x, og = blockIdx.y, kz = blockIdx.z;
  int t = threadIdx.x;
  int o0 = og * 16;
  int c0base = kz * 512;
  int hw = t; int hwc = hw < HW4 ? hw : HW4 - 1;
  __shared__ float wsm[256 * 20];
  float acc[16];
#pragma unroll
  for (int i = 0; i < 16; i++) acc[i] = 0.f;
  for (int c0 = c0base; c0 < c0base + 512; c0 += 256) {
    // stage 256c x 16o: wsm[t*20 + i] = w2[(o0+i)*C4 + c0 + t]
#pragma unroll
    for (int i = 0; i < 16; i++)
      wsm[t * 20 + i] = w2[(size_t)(o0 + i) * C4 + c0 + t];
    __syncthreads();
    const float* xp = x4 + ((size_t)b * C4 + c0) * HW4 + hwc;
#pragma unroll 4
    for (int cc = 0; cc < 256; cc++) {
      float xv = xp[(size_t)cc * HW4];
      const float4* wr = (const float4*)&wsm[cc * 20];
      FMA16(xv, wr);
    }
    __syncthreads();
  }
  if (hw < HW4) {
    float* op = f4p + (size_t)kz * (B8 * HW4 * O4) + ((size_t)(b * HW4 + hw)) * O4 + o0;
    STORE16(op);
  }
}

// ---------------- conv1x1 on x5: f5pT[kz][b][hw][o] (K-split by 4) -----------------
__global__ __launch_bounds__(256) void conv5_kernel(
    const float* __restrict__ x5, const float* __restrict__ w3,
    float* __restrict__ f5p) {
  int b = blockIdx.x, og = blockIdx.y, kz = blockIdx.z;
  int t = threadIdx.x, wv = t >> 6, lane = t & 63;
  int ob = og * 64;
  int o0 = ob + wv * 16;
  int c0base = kz * 512;
  int hw = lane; int hwc = hw < HW5 ? hw : HW5 - 1;
  __shared__ float wsm[64 * 68];
  float acc[16];
#pragma unroll
  for (int i = 0; i < 16; i++) acc[i] = 0.f;
  for (int c0 = c0base; c0 < c0base + 512; c0 += 64) {
    // stage 64c x 64o: wsm[lane*68 + wv + 4i] = w3[(ob+wv+4i)*C5 + c0 + lane]
#pragma unroll
    for (int i = 0; i < 16; i++) {
      int oi = wv + 4 * i;
      wsm[lane * 68 + oi] = w3[(size_t)(ob + oi) * C5 + c0 + lane];
    }
    __syncthreads();
    const float* xp = x5 + ((size_t)b * C5 + c0) * HW5 + hwc;
#pragma unroll 4
    for (int cc = 0; cc < 64; cc++) {
      float xv = xp[(size_t)cc * HW5];
      const float4* wr = (const float4*)&wsm[cc * 68 + wv * 16];
      FMA16(xv, wr);
    }
    __syncthreads();
  }
  if (hw < HW5) {
    float* op = f5p + (size_t)kz * (B8 * HW5 * O5) + ((size_t)(b * HW5 + hw)) * O5 + o0;
    STORE16(op);
  }
}

// ---------------- sum the K-split partials -----------------------------------------
__global__ __launch_bounds__(256) void sum2_kernel(const float* __restrict__ a,
                                                   float* __restrict__ o, int n) {
  int i = blockIdx.x * 256 + threadIdx.x;
  if (i < n) o[i] = a[i] + a[(size_t)n + i];
}
__global__ __launch_bounds__(256) void sum4_kernel(const float* __restrict__ a,
                                                   float* __restrict__ o, int n) {
  int i = blockIdx.x * 256 + threadIdx.x;
  if (i < n) o[i] = a[i] + a[(size_t)n + i] + a[2 * (size_t)n + i] + a[3 * (size_t)n + i];
}

// ---------------- bilinear resize (align-corners linspace) + concat + bias ---------
// writes appT[b][pix][c] channel-contiguous
__global__ __launch_bounds__(256) void resize_kernel(
    const float* __restrict__ f4s, const float* __restrict__ f5s,
    const float* __restrict__ b4, const float* __restrict__ b5,
    float* __restrict__ appT) {
  int pix = blockIdx.x, b = blockIdx.y, t = threadIdx.x;
  int y = pix / HFW, x = pix % HFW;
  float* outp = appT + ((size_t)(b * NPIX + pix)) * CAPP;
  // f4: 14x14 source
  {
    float sy = y * (13.0f / 27.0f), sx = x * (13.0f / 27.0f);
    int y0 = (int)sy, x0 = (int)sx;
    int y1 = min(y0 + 1, 13), x1 = min(x0 + 1, 13);
    float ly = sy - y0, lx = sx - x0;
    float w00 = (1.f - ly) * (1.f - lx), w01 = (1.f - ly) * lx;
    float w10 = ly * (1.f - lx), w11 = ly * lx;
    const float* p00 = f4s + ((size_t)(b * HW4 + y0 * 14 + x0)) * O4;
    const float* p01 = f4s + ((size_t)(b * HW4 + y0 * 14 + x1)) * O4;
    const float* p10 = f4s + ((size_t)(b * HW4 + y1 * 14 + x0)) * O4;
    const float* p11 = f4s + ((size_t)(b * HW4 + y1 * 14 + x1)) * O4;
    for (int c = t; c < O4; c += 256)
      outp[c] = w00 * p00[c] + w01 * p01[c] + w10 * p10[c] + w11 * p11[c] + b4[c];
  }
  // f5: 7x7 source
  {
    float sy = y * (6.0f / 27.0f), sx = x * (6.0f / 27.0f);
    int y0 = (int)sy, x0 = (int)sx;
    int y1 = min(y0 + 1, 6), x1 = min(x0 + 1, 6);
    float ly = sy - y0, lx = sx - x0;
    float w00 = (1.f - ly) * (1.f - lx), w01 = (1.f - ly) * lx;
    float w10 = ly * (1.f - lx), w11 = ly * lx;
    const float* p00 = f5s + ((size_t)(b * HW5 + y0 * 7 + x0)) * O5;
    const float* p01 = f5s + ((size_t)(b * HW5 + y0 * 7 + x1)) * O5;
    const float* p10 = f5s + ((size_t)(b * HW5 + y1 * 7 + x0)) * O5;
    const float* p11 = f5s + ((size_t)(b * HW5 + y1 * 7 + x1)) * O5;
    for (int c = t; c < O5; c += 256)
      outp[O4 + c] = w00 * p00[c] + w01 * p01[c] + w10 * p10[c] + w11 * p11[c] + b5[c];
  }
}

__device__ __forceinline__ float gate_val(const float* sk, int yy, int xx,
                                          float c1w, float c1b, bool use) {
  if (!use) return 1.f;
  float z = sk[yy * HFW + xx] * c1w + c1b;
  return 1.f / (1.f + expf(-z));
}

// ---------------- ROI descriptors: union box, bilinear weights x gate --------------
__global__ __launch_bounds__(64) void desc_kernel(
    const float* __restrict__ boxes, const int* __restrict__ group,
    const int* __restrict__ label, const float* __restrict__ skel,
    const float* __restrict__ c1w_, const float* __restrict__ c1b_,
    float* __restrict__ descw, int* __restrict__ desco) {
  int bg = blockIdx.x, p = threadIdx.x;
  if (p >= 25) return;
  int b = bg >> 3;
  int i1 = group[bg * 2 + 0], i2 = group[bg * 2 + 1];
  const float* bb1 = boxes + (size_t)(b * 16 + i1) * 4;
  const float* bb2 = boxes + (size_t)(b * 16 + i2) * 4;
  float ux1 = fminf(bb1[0], bb2[0]);
  float uy1 = fminf(bb1[1], bb2[1]);
  float ux2 = fmaxf(bb1[2], bb2[2]);
  float uy2 = fmaxf(bb1[3], bb2[3]);
  float rw = fmaxf(ux2 - ux1, 1.0f), rh = fmaxf(uy2 - uy1, 1.0f);
  int iy = p / 5, ix = p % 5;
  float sy = uy1 + (iy + 0.5f) * (rh * 0.2f);
  float sx = ux1 + (ix + 0.5f) * (rw * 0.2f);
  float valid = (sy >= -1.0f && sy <= 28.0f && sx >= -1.0f && sx <= 28.0f) ? 1.f : 0.f;
  float y = fminf(fmaxf(sy, 0.f), 27.f);
  float x = fminf(fmaxf(sx, 0.f), 27.f);
  int y0 = (int)floorf(y), x0 = (int)floorf(x);
  int y1 = min(y0 + 1, 27), x1 = min(x0 + 1, 27);
  float ly = y - (float)y0, lx = x - (float)x0;
  bool use = (label[bg] != -1);
  float c1w = c1w_[0], c1b = c1b_[0];
  const float* sk = skel + (size_t)bg * NPIX;
  int idx = (bg * 25 + p) * 4;
  descw[idx + 0] = (1.f - ly) * (1.f - lx) * valid * gate_val(sk, y0, x0, c1w, c1b, use);
  descw[idx + 1] = (1.f - ly) * lx * valid * gate_val(sk, y0, x1, c1w, c1b, use);
  descw[idx + 2] = ly * (1.f - lx) * valid * gate_val(sk, y1, x0, c1w, c1b, use);
  descw[idx + 3] = ly * lx * valid * gate_val(sk, y1, x1, c1w, c1b, use);
  desco[idx + 0] = y0 * HFW + x0;
  desco[idx + 1] = y0 * HFW + x1;
  desco[idx + 2] = y1 * HFW + x0;
  desco[idx + 3] = y1 * HFW + x1;
}

// ---------------- ROI gather: roisP[bg][p][c], coalesced over c --------------------
__global__ __launch_bounds__(256) void roi_kernel(
    const float* __restrict__ appT, const float* __restrict__ descw,
    const int* __restrict__ desco, float* __restrict__ roisP) {
  int p = blockIdx.x, bg = blockIdx.y;
  int b = bg >> 3;
  int di = (bg * 25 + p) * 4;
  float w0 = descw[di + 0], w1 = descw[di + 1], w2 = descw[di + 2], w3 = descw[di + 3];
  int o0 = desco[di + 0], o1 = desco[di + 1], o2 = desco[di + 2], o3 = desco[di + 3];
  const float* a0 = appT + ((size_t)(b * NPIX + o0)) * CAPP;
  const float* a1 = appT + ((size_t)(b * NPIX + o1)) * CAPP;
  const float* a2 = appT + ((size_t)(b * NPIX + o2)) * CAPP;
  const float* a3 = appT + ((size_t)(b * NPIX + o3)) * CAPP;
  float* out = roisP + ((size_t)(bg * 25 + p)) * CAPP;
  for (int c = threadIdx.x; c < CAPP; c += 256)
    out[c] = w0 * a0[c] + w1 * a1[c] + w2 * a2[c] + w3 * a3[c];
}

// ---------------- LN1 stats (double accumulators) ----------------------------------
__global__ __launch_bounds__(256) void ln1a_kernel(const float* __restrict__ roisP,
                                                   float* __restrict__ stats) {
  int r = blockIdx.x, t = threadIdx.x;
  const float* row = roisP + (size_t)r * D1;
  double s = 0.0, s2 = 0.0;
  for (int k = t; k < D1; k += 256) {
    float v = row[k];
    s += v; s2 += (double)v * v;
  }
  for (int off = 32; off; off >>= 1) {
    s += __shfl_down(s, off);
    s2 += __shfl_down(s2, off);
  }
  __shared__ double red[8];
  int wv = t >> 6;
  if ((t & 63) == 0) { red[wv] = s; red[4 + wv] = s2; }
  __syncthreads();
  if (t == 0) {
    double S = red[0] + red[1] + red[2] + red[3];
    double S2 = red[4] + red[5] + red[6] + red[7];
    double mu = S / D1;
    double var = S2 / D1 - mu * mu;
    stats[r * 2 + 0] = (float)mu;
    stats[r * 2 + 1] = rsqrtf((float)var + 1e-5f);
  }
}

// ---------------- LN1 apply + ReLU + transpose to sknT[k][r] -----------------------
__global__ __launch_bounds__(256) void ln1b_kernel(
    const float* __restrict__ roisP, const float* __restrict__ stats,
    const float* __restrict__ n1w, const float* __restrict__ n1b,
    float* __restrict__ sknT) {
  int o = blockIdx.x * 256 + threadIdx.x;  // o < D1*64 exactly
  int r = o & 63;
  int k = o >> 6;
  unsigned c = (unsigned)k / 25u;
  unsigned p = (unsigned)k - c * 25u;
  float x = roisP[((size_t)(r * 25 + p)) * CAPP + c];
  float mu = stats[r * 2], rs = stats[r * 2 + 1];
  float v = fmaf((x - mu) * rs, n1w[k], n1b[k]);
  sknT[o] = fmaxf(v, 0.f);
}

// ---------------- fc1: split-K GEMM with LDS-staged weights, atomic accumulate -----
__global__ __launch_bounds__(256) void fc1_kernel(
    const float* __restrict__ sknT, const float* __restrict__ w1,
    float* __restrict__ out1T) {
  int jg = blockIdx.x, kc = blockIdx.y;
  int j0 = jg * 64;
  int k0 = kc * 768;
  int t = threadIdx.x, wv = t >> 6, lane = t & 63;
  __shared__ float wsm[128 * 68];
  float acc[16];
#pragma unroll
  for (int i = 0; i < 16; i++) acc[i] = 0.f;
  for (int ss = 0; ss < 6; ss++) {
    int ks = k0 + ss * 128;
#pragma unroll
    for (int i = 0; i < 32; i++) {
      int e = t + i * 256;
      int kk = e & 127, jj = e >> 7;
      wsm[kk * 68 + jj] = w1[(size_t)(j0 + jj) * D1 + ks + kk];
    }
    __syncthreads();
    const float* sp = sknT + (size_t)ks * 64 + lane;
#pragma unroll 2
    for (int kk = 0; kk < 128; kk++) {
      float s = sp[(size_t)kk * 64];
      const float4* wr = (const float4*)&wsm[kk * 68 + wv * 16];
      FMA16(s, wr);
    }
    __syncthreads();
  }
#pragma unroll
  for (int i = 0; i < 16; i++)
    atomicAdd(&out1T[(j0 + wv * 16 + i) * 64 + lane], acc[i]);
}

// ---------------- LN2 + fc2 fused ---------------------------------------------------
__global__ __launch_bounds__(256) void ln2fc2_kernel(
    const float* __restrict__ out1T, const float* __restrict__ b1,
    const float* __restrict__ n2w, const float* __restrict__ n2b,
    const float* __restrict__ w2, const float* __restrict__ b2,
    float* __restrict__ out) {
  int r = blockIdx.x, t = threadIdx.x;
  int j1 = t, j2 = t + 256;
  float v1 = out1T[j1 * 64 + r] + b1[j1];
  float v2 = out1T[j2 * 64 + r] + b1[j2];
  float s = v1 + v2, s2 = v1 * v1 + v2 * v2;
  for (int off = 32; off; off >>= 1) {
    s += __shfl_down(s, off);
    s2 += __shfl_down(s2, off);
  }
  __shared__ float red[8];
  int wv = t >> 6;
  if ((t & 63) == 0) { red[wv] = s; red[4 + wv] = s2; }
  __syncthreads();
  float S = red[0] + red[1] + red[2] + red[3];
  float S2 = red[4] + red[5] + red[6] + red[7];
  float mu = S / 512.f;
  float var = S2 / 512.f - mu * mu;
  float rs = rsqrtf(var + 1e-5f);
  float n1v = fmaf((v1 - mu) * rs, n2w[j1], n2b[j1]);
  float n2v = fmaf((v2 - mu) * rs, n2w[j2], n2b[j2]);
  float pm[6];
#pragma unroll
  for (int m = 0; m < 6; m++)
    pm[m] = n1v * w2[m * 512 + j1] + n2v * w2[m * 512 + j2];
#pragma unroll
  for (int m = 0; m < 6; m++)
    for (int off = 32; off; off >>= 1) pm[m] += __shfl_down(pm[m], off);
  __shared__ float red2[24];
  if ((t & 63) == 0) {
#pragma unroll
    for (int m = 0; m < 6; m++) red2[wv * 6 + m] = pm[m];
  }
  __syncthreads();
  if (t < 6)
    out[r * 6 + t] = red2[t] + red2[6 + t] + red2[12 + t] + red2[18 + t] + b2[t];
}

extern "C" void kernel_launch(void* const* d_in, const int* in_sizes, int n_in,
                              void* d_out, int out_size, void* d_ws, size_t ws_size,
                              hipStream_t stream) {
  const float* x4    = (const float*)d_in[0];
  const float* x5    = (const float*)d_in[1];
  const float* boxes = (const float*)d_in[2];
  const float* skel  = (const float*)d_in[3];
  const int*   group = (const int*)d_in[4];
  // d_in[5] = real_in_num (unused by reference)
  const int*   label = (const int*)d_in[6];
  const float* c1w   = (const float*)d_in[7];
  const float* c1b   = (const float*)d_in[8];
  const float* w2c   = (const float*)d_in[9];
  const float* b2c   = (const float*)d_in[10];
  const float* w3c   = (const float*)d_in[11];
  const float* b3c   = (const float*)d_in[12];
  const float* n1w   = (const float*)d_in[13];
  const float* n1b   = (const float*)d_in[14];
  const float* n2w   = (const float*)d_in[15];
  const float* n2b   = (const float*)d_in[16];
  const float* fw1   = (const float*)d_in[17];
  const float* fb1   = (const float*)d_in[18];
  const float* fw2   = (const float*)d_in[19];
  const float* fb2   = (const float*)d_in[20];
  float* out = (float*)d_out;

  // workspace layout (floats). f4p/f5p partials overlap the appT region (dead by
  // the time resize writes appT).
  float* ws    = (float*)d_ws;
  float* appT  = ws;                         // 9,633,792
  float* f4p   = appT;                       // 2*802,816 (inside appT region)
  float* f5p   = appT + 1605632;             // 4*401,408 (inside appT region)
  float* f4s   = appT + 9633792;             // 802,816
  float* f5s   = f4s + 802816;               // 401,408
  float* descw = f5s + 401408;               // 6,400
  int*   desco = (int*)(descw + 6400);       // 6,400 ints
  float* roisP = descw + 12800;              // 2,457,600
  float* stats = roisP + 2457600;            // 128
  float* sknT  = stats + 128;                // 2,457,600
  float* out1T = sknT + 2457600;             // 32,768

  conv4_kernel<<<dim3(8, 32, 2), 256, 0, stream>>>(x4, w2c, f4p);
  conv5_kernel<<<dim3(8, 16, 4), 256, 0, stream>>>(x5, w3c, f5p);
  sum2_kernel<<<3136, 256, 0, stream>>>(f4p, f4s, 802816);
  sum4_kernel<<<1568, 256, 0, stream>>>(f5p, f5s, 401408);
  resize_kernel<<<dim3(NPIX, B8), 256, 0, stream>>>(f4s, f5s, b2c, b3c, appT);
  desc_kernel<<<NR, 64, 0, stream>>>(boxes, group, label, skel, c1w, c1b, descw, desco);
  roi_kernel<<<dim3(25, NR), 256, 0, stream>>>(appT, descw, desco, roisP);
  ln1a_kernel<<<NR, 256, 0, stream>>>(roisP, stats);
  ln1b_kernel<<<9600, 256, 0, stream>>>(roisP, stats, n1w, n1b, sknT);
  hipMemsetAsync(out1T, 0, 512 * 64 * sizeof(float), stream);
  fc1_kernel<<<dim3(8, 50), 256, 0, stream>>>(sknT, fw1, out1T);
  ln2fc2_kernel<<<NR, 256, 0, stream>>>(out1T, fb1, n2w, n2b, fw2, fb2, out);
}

// Round 2
// 393.275 us; speedup vs baseline: 1.3182x; 1.3182x over previous
//
#include <hip/hip_runtime.h>
#include <math.h>

// Problem constants
#define B8   8
#define HW4  196   // 14*14
#define HW5  49    // 7*7
#define HFW  28
#define NPIX 784   // 28*28
#define CAPP 1536
#define D1   38400 // 1536*25
#define NR   64    // B*G

typedef short short8 __attribute__((ext_vector_type(8)));
typedef float floatx16 __attribute__((ext_vector_type(16)));

__device__ __forceinline__ unsigned short f2bf(float f) {
  // fp32 -> bf16 round-to-nearest-even (inputs are finite, sane scale)
  unsigned u = __float_as_uint(f);
  u += 0x7FFF + ((u >> 16) & 1);
  return (unsigned short)(u >> 16);
}

// ---------------- transpose x4 [8][1024][196] f32 -> x4T [1600 pad][1024] bf16 ----
__global__ __launch_bounds__(256) void t4_kernel(const float* __restrict__ x4,
                                                 unsigned short* __restrict__ x4T) {
  int blk = blockIdx.x;           // b*16 + cc
  int b = blk >> 4, cc = blk & 15;
  int t = threadIdx.x;
  __shared__ float tile[64 * 201];
  for (int i = t; i < 64 * HW4; i += 256) {
    int c = i / HW4, hw = i - c * HW4;
    tile[c * 201 + hw] = x4[((size_t)(b * 1024 + cc * 64 + c)) * HW4 + hw];
  }
  __syncthreads();
  for (int i = t; i < HW4 * 64; i += 256) {
    int hw = i >> 6, c = i & 63;
    x4T[((size_t)(b * HW4 + hw)) * 1024 + cc * 64 + c] = f2bf(tile[c * 201 + hw]);
  }
}

// ---------------- transpose x5 [8][2048][49] f32 -> x5T [448 pad][2048] bf16 ------
__global__ __launch_bounds__(256) void t5_kernel(const float* __restrict__ x5,
                                                 unsigned short* __restrict__ x5T) {
  int blk = blockIdx.x;           // b*32 + cc
  int b = blk >> 5, cc = blk & 31;
  int t = threadIdx.x;
  __shared__ float tile[64 * 51];
  for (int i = t; i < 64 * HW5; i += 256) {
    int c = i / HW5, hw = i - c * HW5;
    tile[c * 51 + hw] = x5[((size_t)(b * 2048 + cc * 64 + c)) * HW5 + hw];
  }
  __syncthreads();
  for (int i = t; i < HW5 * 64; i += 256) {
    int hw = i >> 6, c = i & 63;
    x5T[((size_t)(b * HW5 + hw)) * 2048 + cc * 64 + c] = f2bf(tile[c * 51 + hw]);
  }
}

// ---------------- unified MFMA GEMM: C[m][n] = sum_k A[m][k] * W[n][k] ------------
// A bf16 [Mpad][K] k-contig; W fp32 [N][K] k-contig (cvt to bf16 on the fly).
// Wave-tile: 64m x 32n via two 32x32x16 MFMAs per 16-k step. Split-K partials.
__global__ __launch_bounds__(256) void gemm_bt_kernel(
    const unsigned short* __restrict__ A, const float* __restrict__ Bw,
    float* __restrict__ part,
    int msups, int ntiles, int Mvalid, int Mpad, int N, int K, int kchunk) {
  int w = blockIdx.x * 4 + (threadIdx.x >> 6);
  int lane = threadIdx.x & 63;
  int msup = w % msups; int rest = w / msups;
  int nt = rest % ntiles; int split = rest / ntiles;
  int k0 = split * kchunk;
  int m = lane & 31, koct = (lane >> 5) * 8;
  int r0 = msup * 64 + m;
  int r0c = min(r0, Mvalid - 1);
  int r1c = min(r0 + 32, Mvalid - 1);
  const unsigned short* ap0 = A + (size_t)r0c * K + k0 + koct;
  const unsigned short* ap1 = A + (size_t)r1c * K + k0 + koct;
  const float* bp = Bw + (size_t)(nt * 32 + m) * K + k0 + koct;
  floatx16 acc0, acc1;
#pragma unroll
  for (int i = 0; i < 16; i++) { acc0[i] = 0.f; acc1[i] = 0.f; }
  int ksteps = kchunk >> 4;
#pragma unroll 4
  for (int s = 0; s < ksteps; s++) {
    short8 a0 = *(const short8*)ap0;
    short8 a1 = *(const short8*)ap1;
    float4 b0 = *(const float4*)bp;
    float4 b1 = *(const float4*)(bp + 4);
    short8 bb;
    bb[0] = (short)f2bf(b0.x); bb[1] = (short)f2bf(b0.y);
    bb[2] = (short)f2bf(b0.z); bb[3] = (short)f2bf(b0.w);
    bb[4] = (short)f2bf(b1.x); bb[5] = (short)f2bf(b1.y);
    bb[6] = (short)f2bf(b1.z); bb[7] = (short)f2bf(b1.w);
    acc0 = __builtin_amdgcn_mfma_f32_32x32x16_bf16(a0, bb, acc0, 0, 0, 0);
    acc1 = __builtin_amdgcn_mfma_f32_32x32x16_bf16(a1, bb, acc1, 0, 0, 0);
    ap0 += 16; ap1 += 16; bp += 16;
  }
  // C/D layout (measured m74/m101): col = lane&31, row = (reg&3) + 8*(reg>>2) + 4*(lane>>5)
  float* outp = part + (size_t)split * Mpad * N;
  int col = nt * 32 + m;
  int rbase = msup * 64 + 4 * (lane >> 5);
#pragma unroll
  for (int reg = 0; reg < 16; reg++) {
    int row = rbase + (reg & 3) + 8 * (reg >> 2);
    if (row < Mvalid)      outp[(size_t)row * N + col] = acc0[reg];
    if (row + 32 < Mvalid) outp[(size_t)(row + 32) * N + col] = acc1[reg];
  }
}

// ---------------- sum split-K partials ---------------------------------------------
__global__ __launch_bounds__(256) void reduce_kernel(const float* __restrict__ part,
                                                     float* __restrict__ out,
                                                     int MN, int S) {
  int i = blockIdx.x * 256 + threadIdx.x;
  if (i >= MN) return;
  float s = 0.f;
  for (int j = 0; j < S; j++) s += part[(size_t)j * MN + i];
  out[i] = s;
}

// ---------------- bilinear resize (align-corners linspace) + concat + bias ---------
// writes appT[b][pix][c] channel-contiguous
__global__ __launch_bounds__(256) void resize_kernel(
    const float* __restrict__ f4s, const float* __restrict__ f5s,
    const float* __restrict__ b4, const float* __restrict__ b5,
    float* __restrict__ appT) {
  int pix = blockIdx.x, b = blockIdx.y, t = threadIdx.x;
  int y = pix / HFW, x = pix % HFW;
  float* outp = appT + ((size_t)(b * NPIX + pix)) * CAPP;
  {
    float sy = y * (13.0f / 27.0f), sx = x * (13.0f / 27.0f);
    int y0 = (int)sy, x0 = (int)sx;
    int y1 = min(y0 + 1, 13), x1 = min(x0 + 1, 13);
    float ly = sy - y0, lx = sx - x0;
    float w00 = (1.f - ly) * (1.f - lx), w01 = (1.f - ly) * lx;
    float w10 = ly * (1.f - lx), w11 = ly * lx;
    const float* p00 = f4s + ((size_t)(b * HW4 + y0 * 14 + x0)) * 512;
    const float* p01 = f4s + ((size_t)(b * HW4 + y0 * 14 + x1)) * 512;
    const float* p10 = f4s + ((size_t)(b * HW4 + y1 * 14 + x0)) * 512;
    const float* p11 = f4s + ((size_t)(b * HW4 + y1 * 14 + x1)) * 512;
    for (int c = t; c < 512; c += 256)
      outp[c] = w00 * p00[c] + w01 * p01[c] + w10 * p10[c] + w11 * p11[c] + b4[c];
  }
  {
    float sy = y * (6.0f / 27.0f), sx = x * (6.0f / 27.0f);
    int y0 = (int)sy, x0 = (int)sx;
    int y1 = min(y0 + 1, 6), x1 = min(x0 + 1, 6);
    float ly = sy - y0, lx = sx - x0;
    float w00 = (1.f - ly) * (1.f - lx), w01 = (1.f - ly) * lx;
    float w10 = ly * (1.f - lx), w11 = ly * lx;
    const float* p00 = f5s + ((size_t)(b * HW5 + y0 * 7 + x0)) * 1024;
    const float* p01 = f5s + ((size_t)(b * HW5 + y0 * 7 + x1)) * 1024;
    const float* p10 = f5s + ((size_t)(b * HW5 + y1 * 7 + x0)) * 1024;
    const float* p11 = f5s + ((size_t)(b * HW5 + y1 * 7 + x1)) * 1024;
    for (int c = t; c < 1024; c += 256)
      outp[512 + c] = w00 * p00[c] + w01 * p01[c] + w10 * p10[c] + w11 * p11[c] + b5[c];
  }
}

__device__ __forceinline__ float gate_val(const float* sk, int yy, int xx,
                                          float c1w, float c1b, bool use) {
  if (!use) return 1.f;
  float z = sk[yy * HFW + xx] * c1w + c1b;
  return 1.f / (1.f + expf(-z));
}

// ---------------- ROI descriptors: union box, bilinear weights x gate --------------
__global__ __launch_bounds__(64) void desc_kernel(
    const float* __restrict__ boxes, const int* __restrict__ group,
    const int* __restrict__ label, const float* __restrict__ skel,
    const float* __restrict__ c1w_, const float* __restrict__ c1b_,
    float* __restrict__ descw, int* __restrict__ desco) {
  int bg = blockIdx.x, p = threadIdx.x;
  if (p >= 25) return;
  int b = bg >> 3;
  int i1 = group[bg * 2 + 0], i2 = group[bg * 2 + 1];
  const float* bb1 = boxes + (size_t)(b * 16 + i1) * 4;
  const float* bb2 = boxes + (size_t)(b * 16 + i2) * 4;
  float ux1 = fminf(bb1[0], bb2[0]);
  float uy1 = fminf(bb1[1], bb2[1]);
  float ux2 = fmaxf(bb1[2], bb2[2]);
  float uy2 = fmaxf(bb1[3], bb2[3]);
  float rw = fmaxf(ux2 - ux1, 1.0f), rh = fmaxf(uy2 - uy1, 1.0f);
  int iy = p / 5, ix = p % 5;
  float sy = uy1 + (iy + 0.5f) * (rh * 0.2f);
  float sx = ux1 + (ix + 0.5f) * (rw * 0.2f);
  float valid = (sy >= -1.0f && sy <= 28.0f && sx >= -1.0f && sx <= 28.0f) ? 1.f : 0.f;
  float y = fminf(fmaxf(sy, 0.f), 27.f);
  float x = fminf(fmaxf(sx, 0.f), 27.f);
  int y0 = (int)floorf(y), x0 = (int)floorf(x);
  int y1 = min(y0 + 1, 27), x1 = min(x0 + 1, 27);
  float ly = y - (float)y0, lx = x - (float)x0;
  bool use = (label[bg] != -1);
  float c1w = c1w_[0], c1b = c1b_[0];
  const float* sk = skel + (size_t)bg * NPIX;
  int idx = (bg * 25 + p) * 4;
  descw[idx + 0] = (1.f - ly) * (1.f - lx) * valid * gate_val(sk, y0, x0, c1w, c1b, use);
  descw[idx + 1] = (1.f - ly) * lx * valid * gate_val(sk, y0, x1, c1w, c1b, use);
  descw[idx + 2] = ly * (1.f - lx) * valid * gate_val(sk, y1, x0, c1w, c1b, use);
  descw[idx + 3] = ly * lx * valid * gate_val(sk, y1, x1, c1w, c1b, use);
  desco[idx + 0] = y0 * HFW + x0;
  desco[idx + 1] = y0 * HFW + x1;
  desco[idx + 2] = y1 * HFW + x0;
  desco[idx + 3] = y1 * HFW + x1;
}

// ---------------- ROI gather: roisP[bg][p][c], coalesced over c --------------------
__global__ __launch_bounds__(256) void roi_kernel(
    const float* __restrict__ appT, const float* __restrict__ descw,
    const int* __restrict__ desco, float* __restrict__ roisP) {
  int p = blockIdx.x, bg = blockIdx.y;
  int b = bg >> 3;
  int di = (bg * 25 + p) * 4;
  float w0 = descw[di + 0], w1 = descw[di + 1], w2 = descw[di + 2], w3 = descw[di + 3];
  int o0 = desco[di + 0], o1 = desco[di + 1], o2 = desco[di + 2], o3 = desco[di + 3];
  const float* a0 = appT + ((size_t)(b * NPIX + o0)) * CAPP;
  const float* a1 = appT + ((size_t)(b * NPIX + o1)) * CAPP;
  const float* a2 = appT + ((size_t)(b * NPIX + o2)) * CAPP;
  const float* a3 = appT + ((size_t)(b * NPIX + o3)) * CAPP;
  float* out = roisP + ((size_t)(bg * 25 + p)) * CAPP;
  for (int c = threadIdx.x; c < CAPP; c += 256)
    out[c] = w0 * a0[c] + w1 * a1[c] + w2 * a2[c] + w3 * a3[c];
}

// ---------------- LN1 stats (double accumulators) ----------------------------------
__global__ __launch_bounds__(256) void ln1a_kernel(const float* __restrict__ roisP,
                                                   float* __restrict__ stats) {
  int r = blockIdx.x, t = threadIdx.x;
  const float* row = roisP + (size_t)r * D1;
  double s = 0.0, s2 = 0.0;
  for (int k = t; k < D1; k += 256) {
    float v = row[k];
    s += v; s2 += (double)v * v;
  }
  for (int off = 32; off; off >>= 1) {
    s += __shfl_down(s, off);
    s2 += __shfl_down(s2, off);
  }
  __shared__ double red[8];
  int wv = t >> 6;
  if ((t & 63) == 0) { red[wv] = s; red[4 + wv] = s2; }
  __syncthreads();
  if (t == 0) {
    double S = red[0] + red[1] + red[2] + red[3];
    double S2 = red[4] + red[5] + red[6] + red[7];
    double mu = S / D1;
    double var = S2 / D1 - mu * mu;
    stats[r * 2 + 0] = (float)mu;
    stats[r * 2 + 1] = rsqrtf((float)var + 1e-5f);
  }
}

// ---------------- LN1 apply + ReLU -> sknT bf16 [r][k] (k-contig for MFMA A) -------
__global__ __launch_bounds__(256) void ln1b_kernel(
    const float* __restrict__ roisP, const float* __restrict__ stats,
    const float* __restrict__ n1w, const float* __restrict__ n1b,
    unsigned short* __restrict__ sknT) {
  int o = blockIdx.x * 256 + threadIdx.x;  // 64*38400 exactly
  int r = o / D1;
  int k = o - r * D1;
  unsigned c = (unsigned)k / 25u;
  unsigned p = (unsigned)k - c * 25u;
  float x = roisP[((size_t)(r * 25 + p)) * CAPP + c];
  float mu = stats[r * 2], rs = stats[r * 2 + 1];
  float v = fmaf((x - mu) * rs, n1w[k], n1b[k]);
  sknT[o] = f2bf(fmaxf(v, 0.f));
}

// ---------------- LN2 + fc2 fused (out1 is [64 r][512 j] row-major) ----------------
__global__ __launch_bounds__(256) void ln2fc2_kernel(
    const float* __restrict__ out1, const float* __restrict__ b1,
    const float* __restrict__ n2w, const float* __restrict__ n2b,
    const float* __restrict__ w2, const float* __restrict__ b2,
    float* __restrict__ out) {
  int r = blockIdx.x, t = threadIdx.x;
  int j1 = t, j2 = t + 256;
  float v1 = out1[r * 512 + j1] + b1[j1];
  float v2 = out1[r * 512 + j2] + b1[j2];
  float s = v1 + v2, s2 = v1 * v1 + v2 * v2;
  for (int off = 32; off; off >>= 1) {
    s += __shfl_down(s, off);
    s2 += __shfl_down(s2, off);
  }
  __shared__ float red[8];
  int wv = t >> 6;
  if ((t & 63) == 0) { red[wv] = s; red[4 + wv] = s2; }
  __syncthreads();
  float S = red[0] + red[1] + red[2] + red[3];
  float S2 = red[4] + red[5] + red[6] + red[7];
  float mu = S / 512.f;
  float var = S2 / 512.f - mu * mu;
  float rs = rsqrtf(var + 1e-5f);
  float n1v = fmaf((v1 - mu) * rs, n2w[j1], n2b[j1]);
  float n2v = fmaf((v2 - mu) * rs, n2w[j2], n2b[j2]);
  float pm[6];
#pragma unroll
  for (int m = 0; m < 6; m++)
    pm[m] = n1v * w2[m * 512 + j1] + n2v * w2[m * 512 + j2];
#pragma unroll
  for (int m = 0; m < 6; m++)
    for (int off = 32; off; off >>= 1) pm[m] += __shfl_down(pm[m], off);
  __shared__ float red2[24];
  if ((t & 63) == 0) {
#pragma unroll
    for (int m = 0; m < 6; m++) red2[wv * 6 + m] = pm[m];
  }
  __syncthreads();
  if (t < 6)
    out[r * 6 + t] = red2[t] + red2[6 + t] + red2[12 + t] + red2[18 + t] + b2[t];
}

extern "C" void kernel_launch(void* const* d_in, const int* in_sizes, int n_in,
                              void* d_out, int out_size, void* d_ws, size_t ws_size,
                              hipStream_t stream) {
  const float* x4    = (const float*)d_in[0];
  const float* x5    = (const float*)d_in[1];
  const float* boxes = (const float*)d_in[2];
  const float* skel  = (const float*)d_in[3];
  const int*   group = (const int*)d_in[4];
  const int*   label = (const int*)d_in[6];
  const float* c1w   = (const float*)d_in[7];
  const float* c1b   = (const float*)d_in[8];
  const float* w2c   = (const float*)d_in[9];
  const float* b2c   = (const float*)d_in[10];
  const float* w3c   = (const float*)d_in[11];
  const float* b3c   = (const float*)d_in[12];
  const float* n1w   = (const float*)d_in[13];
  const float* n1b   = (const float*)d_in[14];
  const float* n2w   = (const float*)d_in[15];
  const float* n2b   = (const float*)d_in[16];
  const float* fw1   = (const float*)d_in[17];
  const float* fb1   = (const float*)d_in[18];
  const float* fw2   = (const float*)d_in[19];
  const float* fb2   = (const float*)d_in[20];
  float* out = (float*)d_out;

  // workspace layout (float offsets). regionA is time-shared:
  //   part4+part5 (gemms) -> appT (resize..roi) -> part1 (fc1)
  float* ws    = (float*)d_ws;
  float* regionA = ws;                         // 9,633,792 floats
  float* part4 = regionA;                      // 4*1600*512   = 3,276,800
  float* part5 = regionA + 3276800;            // 8*448*1024   = 3,670,016
  float* part1 = regionA;                      // 200*64*512   = 6,553,600
  float* appT  = regionA;                      // 8*784*1536   = 9,633,792
  float* f4T   = ws + 9633792;                 // 1600*512     =   819,200
  float* f5T   = f4T + 819200;                 // 448*1024     =   458,752
  float* descw = ws + 10911744;                // 6,400
  int*   desco = (int*)(descw + 6400);         // 6,400
  float* roisP = ws + 10924544;                // 64*25*1536   = 2,457,600
  unsigned short* x4T = (unsigned short*)roisP;              // inside roisP (dead before roi)
  unsigned short* x5T = (unsigned short*)(roisP + 819200);   // inside roisP
  float* stats = ws + 13382144;                // 128
  unsigned short* sknT = (unsigned short*)(ws + 13382272);   // 64*38400 bf16 = 1,228,800 f
  float* out1  = ws + 14611072;                // 64*512 = 32,768  (total 14,643,840 f = 58.6 MB)

  t4_kernel<<<128, 256, 0, stream>>>(x4, x4T);
  t5_kernel<<<256, 256, 0, stream>>>(x5, x5T);
  // conv4: M=1568(pad 1600), N=512, K=1024, split 4 x kchunk 256  -> 1600 waves
  gemm_bt_kernel<<<400, 256, 0, stream>>>(x4T, w2c, part4, 25, 16, 1568, 1600, 512, 1024, 256);
  // conv5: M=392(pad 448), N=1024, K=2048, split 8 x kchunk 256   -> 1792 waves
  gemm_bt_kernel<<<448, 256, 0, stream>>>(x5T, w3c, part5, 7, 32, 392, 448, 1024, 2048, 256);
  reduce_kernel<<<3200, 256, 0, stream>>>(part4, f4T, 819200, 4);
  reduce_kernel<<<1792, 256, 0, stream>>>(part5, f5T, 458752, 8);
  resize_kernel<<<dim3(NPIX, B8), 256, 0, stream>>>(f4T, f5T, b2c, b3c, appT);
  desc_kernel<<<NR, 64, 0, stream>>>(boxes, group, label, skel, c1w, c1b, descw, desco);
  roi_kernel<<<dim3(25, NR), 256, 0, stream>>>(appT, descw, desco, roisP);
  ln1a_kernel<<<NR, 256, 0, stream>>>(roisP, stats);
  ln1b_kernel<<<9600, 256, 0, stream>>>(roisP, stats, n1w, n1b, sknT);
  // fc1: M=64, N=512, K=38400, split 200 x kchunk 192             -> 3200 waves
  gemm_bt_kernel<<<800, 256, 0, stream>>>(sknT, fw1, part1, 1, 16, 64, 64, 512, 38400, 192);
  reduce_kernel<<<128, 256, 0, stream>>>(part1, out1, 32768, 200);
  ln2fc2_kernel<<<NR, 256, 0, stream>>>(out1, fb1, n2w, n2b, fw2, fb2, out);
}

// Round 4
// 311.639 us; speedup vs baseline: 1.6635x; 1.2620x over previous
//
#include <hip/hip_runtime.h>
#include <math.h>

// Problem constants
#define B8   8
#define HW4  196   // 14*14
#define HW5  49    // 7*7
#define HFW  28
#define NPIX 784   // 28*28
#define CAPP 1536
#define D1   38400 // 1536*25
#define NR   64    // B*G

typedef short short8 __attribute__((ext_vector_type(8)));
typedef short short4v __attribute__((ext_vector_type(4)));
typedef float floatx16 __attribute__((ext_vector_type(16)));

__device__ __forceinline__ unsigned short f2bf(float f) {
  unsigned u = __float_as_uint(f);
  u += 0x7FFF + ((u >> 16) & 1);
  return (unsigned short)(u >> 16);
}

// ---------------- transpose x4 [8][1024][196] f32 -> x4T [1600 pad][1024] bf16 ----
__global__ __launch_bounds__(256) void t4_kernel(const float* __restrict__ x4,
                                                 unsigned short* __restrict__ x4T) {
  int blk = blockIdx.x;           // b*16 + cc
  int b = blk >> 4, cc = blk & 15;
  int t = threadIdx.x;
  __shared__ float tile[64 * 201];
  for (int i = t; i < 64 * HW4; i += 256) {
    int c = i / HW4, hw = i - c * HW4;
    tile[c * 201 + hw] = x4[((size_t)(b * 1024 + cc * 64 + c)) * HW4 + hw];
  }
  __syncthreads();
  for (int i = t; i < HW4 * 64; i += 256) {
    int hw = i >> 6, c = i & 63;
    x4T[((size_t)(b * HW4 + hw)) * 1024 + cc * 64 + c] = f2bf(tile[c * 201 + hw]);
  }
}

// ---------------- transpose x5 [8][2048][49] f32 -> x5T [448 pad][2048] bf16 ------
__global__ __launch_bounds__(256) void t5_kernel(const float* __restrict__ x5,
                                                 unsigned short* __restrict__ x5T) {
  int blk = blockIdx.x;           // b*32 + cc
  int b = blk >> 5, cc = blk & 31;
  int t = threadIdx.x;
  __shared__ float tile[64 * 51];
  for (int i = t; i < 64 * HW5; i += 256) {
    int c = i / HW5, hw = i - c * HW5;
    tile[c * 51 + hw] = x5[((size_t)(b * 2048 + cc * 64 + c)) * HW5 + hw];
  }
  __syncthreads();
  for (int i = t; i < HW5 * 64; i += 256) {
    int hw = i >> 6, c = i & 63;
    x5T[((size_t)(b * HW5 + hw)) * 2048 + cc * 64 + c] = f2bf(tile[c * 51 + hw]);
  }
}

// ---------------- LDS-staged dbuf MFMA GEMM: C[m][n] = sum_k A[m][k]*W[n][k] ------
// A bf16 [mtiles*64][K] k-contig; W fp32 [N][K] k-contig (cvt bf16 at stage time).
// Block: 64m x 64n, 4 waves (wave = 32m x 32n), BK=64, double-buffered LDS,
// next-tile loads issued before current-tile compute. kchunk = split-K chunk (%64==0).
__global__ __launch_bounds__(256) void gemm_kernel(
    const unsigned short* __restrict__ A, const float* __restrict__ Bw,
    float* __restrict__ part,
    int mtiles, int ntiles, int Mvalid, int N, int K, int kchunk) {
  __shared__ unsigned short As[2][8][64][8];  // [buf][ko][m][j]
  __shared__ unsigned short Bs[2][8][64][8];  // [buf][ko][n][j]
  int bid = blockIdx.x;
  int mt = bid % mtiles; int rest = bid / mtiles;
  int nt = rest % ntiles; int sp = rest / ntiles;
  int k0 = sp * kchunk;
  int nkb = kchunk >> 6;
  int t = threadIdx.x;
  int wave = t >> 6, lane = t & 63;
  int wm = wave & 1, wn = wave >> 1;

  const unsigned short* Aptr = A + (size_t)(mt * 64) * K + k0;
  const float* Bptr = Bw + (size_t)(nt * 64) * K + k0;

  short8 areg[2];
  float4 breg[4];

  floatx16 acc;
#pragma unroll
  for (int i = 0; i < 16; i++) acc[i] = 0.f;

  // prologue: stage kb=0
#pragma unroll
  for (int i = 0; i < 2; i++) {
    int e = t + i * 256;
    areg[i] = *(const short8*)(Aptr + (size_t)(e >> 3) * K + (e & 7) * 8);
  }
#pragma unroll
  for (int i = 0; i < 4; i++) {
    int e = t + i * 256;
    breg[i] = *(const float4*)(Bptr + (size_t)(e >> 4) * K + (e & 15) * 4);
  }
#pragma unroll
  for (int i = 0; i < 2; i++) {
    int e = t + i * 256;
    *(short8*)&As[0][e & 7][e >> 3][0] = areg[i];
  }
#pragma unroll
  for (int i = 0; i < 4; i++) {
    int e = t + i * 256;
    short4v v;
    v[0] = (short)f2bf(breg[i].x); v[1] = (short)f2bf(breg[i].y);
    v[2] = (short)f2bf(breg[i].z); v[3] = (short)f2bf(breg[i].w);
    *(short4v*)&Bs[0][(e & 15) >> 1][e >> 4][((e & 15) & 1) * 4] = v;
  }
  __syncthreads();

  for (int kb = 0; kb < nkb; kb++) {
    int buf = kb & 1;
    bool more = (kb + 1) < nkb;
    if (more) {
      int kof = (kb + 1) * 64;
#pragma unroll
      for (int i = 0; i < 2; i++) {
        int e = t + i * 256;
        areg[i] = *(const short8*)(Aptr + (size_t)(e >> 3) * K + kof + (e & 7) * 8);
      }
#pragma unroll
      for (int i = 0; i < 4; i++) {
        int e = t + i * 256;
        breg[i] = *(const float4*)(Bptr + (size_t)(e >> 4) * K + kof + (e & 15) * 4);
      }
    }
    // compute current buffer: 4 k-steps of 16
#pragma unroll
    for (int s = 0; s < 4; s++) {
      short8 af = *(const short8*)&As[buf][2 * s + (lane >> 5)][wm * 32 + (lane & 31)][0];
      short8 bf = *(const short8*)&Bs[buf][2 * s + (lane >> 5)][wn * 32 + (lane & 31)][0];
      acc = __builtin_amdgcn_mfma_f32_32x32x16_bf16(af, bf, acc, 0, 0, 0);
    }
    __syncthreads();
    if (more) {
      int nb = 1 - buf;
#pragma unroll
      for (int i = 0; i < 2; i++) {
        int e = t + i * 256;
        *(short8*)&As[nb][e & 7][e >> 3][0] = areg[i];
      }
#pragma unroll
      for (int i = 0; i < 4; i++) {
        int e = t + i * 256;
        short4v v;
        v[0] = (short)f2bf(breg[i].x); v[1] = (short)f2bf(breg[i].y);
        v[2] = (short)f2bf(breg[i].z); v[3] = (short)f2bf(breg[i].w);
        *(short4v*)&Bs[nb][(e & 15) >> 1][e >> 4][((e & 15) & 1) * 4] = v;
      }
      __syncthreads();
    }
  }

  // store: C/D layout col=lane&31, row=(reg&3)+8*(reg>>2)+4*(lane>>5)
  float* outp = part + (size_t)sp * (mtiles * 64) * N;
  int col = nt * 64 + wn * 32 + (lane & 31);
  int rbase = mt * 64 + wm * 32 + 4 * (lane >> 5);
#pragma unroll
  for (int reg = 0; reg < 16; reg++) {
    int row = rbase + (reg & 3) + 8 * (reg >> 2);
    if (row < Mvalid) outp[(size_t)row * N + col] = acc[reg];
  }
}

// ---------------- sum split-K partials ---------------------------------------------
__global__ __launch_bounds__(256) void reduce_kernel(const float* __restrict__ part,
                                                     float* __restrict__ out,
                                                     int MN, int S) {
  int i = blockIdx.x * 256 + threadIdx.x;
  if (i >= MN) return;
  float s = 0.f;
  for (int j = 0; j < S; j++) s += part[(size_t)j * MN + i];
  out[i] = s;
}

// ---------------- per-pixel resize tap tables (pixel -> 4 src offsets + weights) ---
__global__ __launch_bounds__(256) void taps_kernel(
    float* __restrict__ tap4w, int* __restrict__ tap4o,
    float* __restrict__ tap5w, int* __restrict__ tap5o) {
  int pix = blockIdx.x * 256 + threadIdx.x;
  if (pix >= NPIX) return;
  int y = pix / HFW, x = pix % HFW;
  {
    float sy = y * (13.0f / 27.0f), sx = x * (13.0f / 27.0f);
    int y0 = (int)sy, x0 = (int)sx;
    int y1 = min(y0 + 1, 13), x1 = min(x0 + 1, 13);
    float ly = sy - y0, lx = sx - x0;
    tap4o[pix * 4 + 0] = y0 * 14 + x0; tap4w[pix * 4 + 0] = (1.f - ly) * (1.f - lx);
    tap4o[pix * 4 + 1] = y0 * 14 + x1; tap4w[pix * 4 + 1] = (1.f - ly) * lx;
    tap4o[pix * 4 + 2] = y1 * 14 + x0; tap4w[pix * 4 + 2] = ly * (1.f - lx);
    tap4o[pix * 4 + 3] = y1 * 14 + x1; tap4w[pix * 4 + 3] = ly * lx;
  }
  {
    float sy = y * (6.0f / 27.0f), sx = x * (6.0f / 27.0f);
    int y0 = (int)sy, x0 = (int)sx;
    int y1 = min(y0 + 1, 6), x1 = min(x0 + 1, 6);
    float ly = sy - y0, lx = sx - x0;
    tap5o[pix * 4 + 0] = y0 * 7 + x0; tap5w[pix * 4 + 0] = (1.f - ly) * (1.f - lx);
    tap5o[pix * 4 + 1] = y0 * 7 + x1; tap5w[pix * 4 + 1] = (1.f - ly) * lx;
    tap5o[pix * 4 + 2] = y1 * 7 + x0; tap5w[pix * 4 + 2] = ly * (1.f - lx);
    tap5o[pix * 4 + 3] = y1 * 7 + x1; tap5w[pix * 4 + 3] = ly * lx;
  }
}

__device__ __forceinline__ float gate_val(const float* sk, int yy, int xx,
                                          float c1w, float c1b, bool use) {
  if (!use) return 1.f;
  float z = sk[yy * HFW + xx] * c1w + c1b;
  return 1.f / (1.f + expf(-z));
}

// ---------------- ROI descriptors: union box, bilinear weights x gate --------------
__global__ __launch_bounds__(64) void desc_kernel(
    const float* __restrict__ boxes, const int* __restrict__ group,
    const int* __restrict__ label, const float* __restrict__ skel,
    const float* __restrict__ c1w_, const float* __restrict__ c1b_,
    float* __restrict__ descw, int* __restrict__ desco) {
  int bg = blockIdx.x, p = threadIdx.x;
  if (p >= 25) return;
  int b = bg >> 3;
  int i1 = group[bg * 2 + 0], i2 = group[bg * 2 + 1];
  const float* bb1 = boxes + (size_t)(b * 16 + i1) * 4;
  const float* bb2 = boxes + (size_t)(b * 16 + i2) * 4;
  float ux1 = fminf(bb1[0], bb2[0]);
  float uy1 = fminf(bb1[1], bb2[1]);
  float ux2 = fmaxf(bb1[2], bb2[2]);
  float uy2 = fmaxf(bb1[3], bb2[3]);
  float rw = fmaxf(ux2 - ux1, 1.0f), rh = fmaxf(uy2 - uy1, 1.0f);
  int iy = p / 5, ix = p % 5;
  float sy = uy1 + (iy + 0.5f) * (rh * 0.2f);
  float sx = ux1 + (ix + 0.5f) * (rw * 0.2f);
  float valid = (sy >= -1.0f && sy <= 28.0f && sx >= -1.0f && sx <= 28.0f) ? 1.f : 0.f;
  float y = fminf(fmaxf(sy, 0.f), 27.f);
  float x = fminf(fmaxf(sx, 0.f), 27.f);
  int y0 = (int)floorf(y), x0 = (int)floorf(x);
  int y1 = min(y0 + 1, 27), x1 = min(x0 + 1, 27);
  float ly = y - (float)y0, lx = x - (float)x0;
  bool use = (label[bg] != -1);
  float c1w = c1w_[0], c1b = c1b_[0];
  const float* sk = skel + (size_t)bg * NPIX;
  int idx = (bg * 25 + p) * 4;
  descw[idx + 0] = (1.f - ly) * (1.f - lx) * valid * gate_val(sk, y0, x0, c1w, c1b, use);
  descw[idx + 1] = (1.f - ly) * lx * valid * gate_val(sk, y0, x1, c1w, c1b, use);
  descw[idx + 2] = ly * (1.f - lx) * valid * gate_val(sk, y1, x0, c1w, c1b, use);
  descw[idx + 3] = ly * lx * valid * gate_val(sk, y1, x1, c1w, c1b, use);
  desco[idx + 0] = y0 * HFW + x0;
  desco[idx + 1] = y0 * HFW + x1;
  desco[idx + 2] = y1 * HFW + x0;
  desco[idx + 3] = y1 * HFW + x1;
}

// ---------------- fused resize+ROI: 16 composed taps directly on f4T/f5T -----------
// roisP[bg*25+p][c] = sum_i wg_i * (resize(conv)[pix_i][c] + bias[c])
//                   = sum_{i,j} (wg_i * tapw_ij) * fT[off_ij][c] + (sum_i wg_i)*bias[c]
__global__ __launch_bounds__(256) void roi_kernel(
    const float* __restrict__ f4T, const float* __restrict__ f5T,
    const float* __restrict__ descw, const int* __restrict__ desco,
    const float* __restrict__ tap4w, const int* __restrict__ tap4o,
    const float* __restrict__ tap5w, const int* __restrict__ tap5o,
    const float* __restrict__ b4, const float* __restrict__ b5,
    float* __restrict__ roisP) {
  int p = blockIdx.x, bg = blockIdx.y, b = bg >> 3, t = threadIdx.x;
  __shared__ float cw4[16], cw5[16], wgs;
  __shared__ int co4[16], co5[16];
  int di = (bg * 25 + p) * 4;
  if (t < 16) {
    int i = t >> 2, j = t & 3;
    float wg = descw[di + i];
    int pix = desco[di + i];
    cw4[t] = wg * tap4w[pix * 4 + j];
    co4[t] = (b * HW4 + tap4o[pix * 4 + j]) * 512;
    cw5[t] = wg * tap5w[pix * 4 + j];
    co5[t] = (b * HW5 + tap5o[pix * 4 + j]) * 1024;
  }
  if (t == 16) wgs = descw[di] + descw[di + 1] + descw[di + 2] + descw[di + 3];
  __syncthreads();
  float w4r[16], w5r[16];
  int o4r[16], o5r[16];
  float wg = wgs;
#pragma unroll
  for (int i = 0; i < 16; i++) {
    w4r[i] = cw4[i]; o4r[i] = co4[i];
    w5r[i] = cw5[i]; o5r[i] = co5[i];
  }
  float* outp = roisP + (size_t)(bg * 25 + p) * CAPP;
  for (int c = t; c < 512; c += 256) {
    float acc = wg * b4[c];
#pragma unroll
    for (int i = 0; i < 16; i++) acc = fmaf(w4r[i], f4T[o4r[i] + c], acc);
    outp[c] = acc;
  }
  for (int c = t; c < 1024; c += 256) {
    float acc = wg * b5[c];
#pragma unroll
    for (int i = 0; i < 16; i++) acc = fmaf(w5r[i], f5T[o5r[i] + c], acc);
    outp[512 + c] = acc;
  }
}

// ---------------- LN1 stats (double accumulators) ----------------------------------
__global__ __launch_bounds__(256) void ln1a_kernel(const float* __restrict__ roisP,
                                                   float* __restrict__ stats) {
  int r = blockIdx.x, t = threadIdx.x;
  const float* row = roisP + (size_t)r * D1;
  double s = 0.0, s2 = 0.0;
  for (int k = t; k < D1; k += 256) {
    float v = row[k];
    s += v; s2 += (double)v * v;
  }
  for (int off = 32; off; off >>= 1) {
    s += __shfl_down(s, off);
    s2 += __shfl_down(s2, off);
  }
  __shared__ double red[8];
  int wv = t >> 6;
  if ((t & 63) == 0) { red[wv] = s; red[4 + wv] = s2; }
  __syncthreads();
  if (t == 0) {
    double S = red[0] + red[1] + red[2] + red[3];
    double S2 = red[4] + red[5] + red[6] + red[7];
    double mu = S / D1;
    double var = S2 / D1 - mu * mu;
    stats[r * 2 + 0] = (float)mu;
    stats[r * 2 + 1] = rsqrtf((float)var + 1e-5f);
  }
}

// ---------------- LN1 apply + ReLU -> sknT bf16 [r][k] (k-contig for MFMA A) -------
__global__ __launch_bounds__(256) void ln1b_kernel(
    const float* __restrict__ roisP, const float* __restrict__ stats,
    const float* __restrict__ n1w, const float* __restrict__ n1b,
    unsigned short* __restrict__ sknT) {
  int o = blockIdx.x * 256 + threadIdx.x;  // 64*38400 exactly
  int r = o / D1;
  int k = o - r * D1;
  unsigned c = (unsigned)k / 25u;
  unsigned p = (unsigned)k - c * 25u;
  float x = roisP[((size_t)(r * 25 + p)) * CAPP + c];
  float mu = stats[r * 2], rs = stats[r * 2 + 1];
  float v = fmaf((x - mu) * rs, n1w[k], n1b[k]);
  sknT[o] = f2bf(fmaxf(v, 0.f));
}

// ---------------- LN2 + fc2 fused (out1 is [64 r][512 j] row-major) ----------------
__global__ __launch_bounds__(256) void ln2fc2_kernel(
    const float* __restrict__ out1, const float* __restrict__ b1,
    const float* __restrict__ n2w, const float* __restrict__ n2b,
    const float* __restrict__ w2, const float* __restrict__ b2,
    float* __restrict__ out) {
  int r = blockIdx.x, t = threadIdx.x;
  int j1 = t, j2 = t + 256;
  float v1 = out1[r * 512 + j1] + b1[j1];
  float v2 = out1[r * 512 + j2] + b1[j2];
  float s = v1 + v2, s2 = v1 * v1 + v2 * v2;
  for (int off = 32; off; off >>= 1) {
    s += __shfl_down(s, off);
    s2 += __shfl_down(s2, off);
  }
  __shared__ float red[8];
  int wv = t >> 6;
  if ((t & 63) == 0) { red[wv] = s; red[4 + wv] = s2; }
  __syncthreads();
  float S = red[0] + red[1] + red[2] + red[3];
  float S2 = red[4] + red[5] + red[6] + red[7];
  float mu = S / 512.f;
  float var = S2 / 512.f - mu * mu;
  float rs = rsqrtf(var + 1e-5f);
  float n1v = fmaf((v1 - mu) * rs, n2w[j1], n2b[j1]);
  float n2v = fmaf((v2 - mu) * rs, n2w[j2], n2b[j2]);
  float pm[6];
#pragma unroll
  for (int m = 0; m < 6; m++)
    pm[m] = n1v * w2[m * 512 + j1] + n2v * w2[m * 512 + j2];
#pragma unroll
  for (int m = 0; m < 6; m++)
    for (int off = 32; off; off >>= 1) pm[m] += __shfl_down(pm[m], off);
  __shared__ float red2[24];
  if ((t & 63) == 0) {
#pragma unroll
    for (int m = 0; m < 6; m++) red2[wv * 6 + m] = pm[m];
  }
  __syncthreads();
  if (t < 6)
    out[r * 6 + t] = red2[t] + red2[6 + t] + red2[12 + t] + red2[18 + t] + b2[t];
}

extern "C" void kernel_launch(void* const* d_in, const int* in_sizes, int n_in,
                              void* d_out, int out_size, void* d_ws, size_t ws_size,
                              hipStream_t stream) {
  const float* x4    = (const float*)d_in[0];
  const float* x5    = (const float*)d_in[1];
  const float* boxes = (const float*)d_in[2];
  const float* skel  = (const float*)d_in[3];
  const int*   group = (const int*)d_in[4];
  const int*   label = (const int*)d_in[6];
  const float* c1w   = (const float*)d_in[7];
  const float* c1b   = (const float*)d_in[8];
  const float* w2c   = (const float*)d_in[9];
  const float* b2c   = (const float*)d_in[10];
  const float* w3c   = (const float*)d_in[11];
  const float* b3c   = (const float*)d_in[12];
  const float* n1w   = (const float*)d_in[13];
  const float* n1b   = (const float*)d_in[14];
  const float* n2w   = (const float*)d_in[15];
  const float* n2b   = (const float*)d_in[16];
  const float* fw1   = (const float*)d_in[17];
  const float* fb1   = (const float*)d_in[18];
  const float* fw2   = (const float*)d_in[19];
  const float* fb2   = (const float*)d_in[20];
  float* out = (float*)d_out;

  // workspace layout — ALL offsets in FLOAT units (bf16 arrays noted in shorts).
  // R3 bug: x5T was at +409600 f, inside x4T's 819200 f — fixed here.
  float* ws = (float*)d_ws;
  unsigned short* x4T = (unsigned short*)ws;              // 1600*1024 sh = 819200 f
  unsigned short* x5T = (unsigned short*)(ws + 819200);   // 448*2048 sh  = 458752 f
  float* part4 = ws + 1277952;             // 2*1600*512  = 1,638,400
  float* part1 = part4;                    // 75*64*512   = 2,457,600 (extends into dead part5)
  float* part5 = ws + 2916352;             // 4*448*1024  = 1,835,008
  float* f4T   = ws + 4751360;             // 1568(+pad)*512 = 819,200
  float* f5T   = ws + 5570560;             // 448*1024    =   458,752
  float* tap4w = ws + 6029312;             // 3136
  int*   tap4o = (int*)(ws + 6032448);     // 3136
  float* tap5w = ws + 6035584;             // 3136
  int*   tap5o = (int*)(ws + 6038720);     // 3136
  float* descw = ws + 6041856;             // 6400
  int*   desco = (int*)(ws + 6048256);     // 6400
  float* roisP = ws + 6054656;             // 64*25*1536  = 2,457,600
  float* stats = ws + 8512256;             // 128
  unsigned short* sknT = (unsigned short*)(ws + 8512384); // 64*38400 sh = 1,228,800 f
  float* out1  = ws + 9741184;             // 64*512 = 32,768  (end: 9,773,952 f = 39.1 MB)

  t4_kernel<<<128, 256, 0, stream>>>(x4, x4T);
  t5_kernel<<<256, 256, 0, stream>>>(x5, x5T);
  taps_kernel<<<4, 256, 0, stream>>>(tap4w, tap4o, tap5w, tap5o);
  desc_kernel<<<NR, 64, 0, stream>>>(boxes, group, label, skel, c1w, c1b, descw, desco);
  // conv4: M=1568 (25 mtiles), N=512 (8 ntiles), K=1024, split 2 x kchunk 512
  gemm_kernel<<<25 * 8 * 2, 256, 0, stream>>>(x4T, w2c, part4, 25, 8, 1568, 512, 1024, 512);
  // conv5: M=392 (7 mtiles), N=1024 (16 ntiles), K=2048, split 4 x kchunk 512
  gemm_kernel<<<7 * 16 * 4, 256, 0, stream>>>(x5T, w3c, part5, 7, 16, 392, 1024, 2048, 512);
  reduce_kernel<<<3200, 256, 0, stream>>>(part4, f4T, 819200, 2);
  reduce_kernel<<<1792, 256, 0, stream>>>(part5, f5T, 458752, 4);
  roi_kernel<<<dim3(25, NR), 256, 0, stream>>>(f4T, f5T, descw, desco,
                                               tap4w, tap4o, tap5w, tap5o,
                                               b2c, b3c, roisP);
  ln1a_kernel<<<NR, 256, 0, stream>>>(roisP, stats);
  ln1b_kernel<<<9600, 256, 0, stream>>>(roisP, stats, n1w, n1b, sknT);
  // fc1: M=64 (1 mtile), N=512 (8 ntiles), K=38400, split 75 x kchunk 512
  gemm_kernel<<<1 * 8 * 75, 256, 0, stream>>>(sknT, fw1, part1, 1, 8, 64, 512, 38400, 512);
  reduce_kernel<<<128, 256, 0, stream>>>(part1, out1, 32768, 75);
  ln2fc2_kernel<<<NR, 256, 0, stream>>>(out1, fb1, n2w, n2b, fw2, fb2, out);
}

// Round 5
// 267.830 us; speedup vs baseline: 1.9356x; 1.1636x over previous
//
#include <hip/hip_runtime.h>
#include <math.h>

// Problem constants
#define B8   8
#define HW4  196   // 14*14
#define HW5  49    // 7*7
#define HFW  28
#define NPIX 784   // 28*28
#define CAPP 1536
#define D1   38400 // 1536*25
#define NR   64    // B*G

typedef short short8 __attribute__((ext_vector_type(8)));
typedef short short4v __attribute__((ext_vector_type(4)));
typedef float floatx16 __attribute__((ext_vector_type(16)));

__device__ __forceinline__ unsigned short f2bf(float f) {
  unsigned u = __float_as_uint(f);
  u += 0x7FFF + ((u >> 16) & 1);
  return (unsigned short)(u >> 16);
}

// ---------------- fused transpose: x4 and x5 -> bf16 k-contiguous rows -------------
// blocks 0..127: x4 [8][1024][196] -> x4T[b*196+hw][1024]
// blocks 128..383: x5 [8][2048][49] -> x5T[b*49+hw][2048]
__global__ __launch_bounds__(256) void tt_kernel(
    const float* __restrict__ x4, const float* __restrict__ x5,
    unsigned short* __restrict__ x4T, unsigned short* __restrict__ x5T) {
  __shared__ float tile[64 * 201];
  int blk = blockIdx.x, t = threadIdx.x;
  if (blk < 128) {
    int b = blk >> 4, cc = blk & 15;
    for (int i = t; i < 64 * HW4; i += 256) {
      int c = i / HW4, hw = i - c * HW4;
      tile[c * 201 + hw] = x4[((size_t)(b * 1024 + cc * 64 + c)) * HW4 + hw];
    }
    __syncthreads();
    for (int i = t; i < HW4 * 64; i += 256) {
      int hw = i >> 6, c = i & 63;
      x4T[((size_t)(b * HW4 + hw)) * 1024 + cc * 64 + c] = f2bf(tile[c * 201 + hw]);
    }
  } else {
    int blk2 = blk - 128;
    int b = blk2 >> 5, cc = blk2 & 31;
    for (int i = t; i < 64 * HW5; i += 256) {
      int c = i / HW5, hw = i - c * HW5;
      tile[c * 51 + hw] = x5[((size_t)(b * 2048 + cc * 64 + c)) * HW5 + hw];
    }
    __syncthreads();
    for (int i = t; i < HW5 * 64; i += 256) {
      int hw = i >> 6, c = i & 63;
      x5T[((size_t)(b * HW5 + hw)) * 2048 + cc * 64 + c] = f2bf(tile[c * 51 + hw]);
    }
  }
}

// ---------------- LDS-staged dbuf MFMA GEMM, atomic accumulate -------------------
// C[m][n] += sum_k A[m][k]*W[n][k]   (C must be zeroed before launch)
// A bf16 [mtiles*64][K] k-contig; W fp32 [N][K] k-contig (cvt bf16 at stage time).
// Block: 64m x 64n, 4 waves, BK=64, dbuf LDS. blocks = mtiles*ntiles*splits.
__global__ __launch_bounds__(256) void gemm_kernel(
    const unsigned short* __restrict__ A, const float* __restrict__ Bw,
    float* __restrict__ C,
    int mtiles, int ntiles, int Mvalid, int N, int K, int kchunk) {
  __shared__ unsigned short As[2][8][64][8];  // [buf][ko][m][j]
  __shared__ unsigned short Bs[2][8][64][8];  // [buf][ko][n][j]
  int bid = blockIdx.x;
  int mt = bid % mtiles; int rest = bid / mtiles;
  int nt = rest % ntiles; int sp = rest / ntiles;
  int k0 = sp * kchunk;
  int nkb = kchunk >> 6;
  int t = threadIdx.x;
  int wave = t >> 6, lane = t & 63;
  int wm = wave & 1, wn = wave >> 1;

  const unsigned short* Aptr = A + (size_t)(mt * 64) * K + k0;
  const float* Bptr = Bw + (size_t)(nt * 64) * K + k0;

  short8 areg[2];
  float4 breg[4];

  floatx16 acc;
#pragma unroll
  for (int i = 0; i < 16; i++) acc[i] = 0.f;

  // prologue: stage kb=0
#pragma unroll
  for (int i = 0; i < 2; i++) {
    int e = t + i * 256;
    areg[i] = *(const short8*)(Aptr + (size_t)(e >> 3) * K + (e & 7) * 8);
  }
#pragma unroll
  for (int i = 0; i < 4; i++) {
    int e = t + i * 256;
    breg[i] = *(const float4*)(Bptr + (size_t)(e >> 4) * K + (e & 15) * 4);
  }
#pragma unroll
  for (int i = 0; i < 2; i++) {
    int e = t + i * 256;
    *(short8*)&As[0][e & 7][e >> 3][0] = areg[i];
  }
#pragma unroll
  for (int i = 0; i < 4; i++) {
    int e = t + i * 256;
    short4v v;
    v[0] = (short)f2bf(breg[i].x); v[1] = (short)f2bf(breg[i].y);
    v[2] = (short)f2bf(breg[i].z); v[3] = (short)f2bf(breg[i].w);
    *(short4v*)&Bs[0][(e & 15) >> 1][e >> 4][((e & 15) & 1) * 4] = v;
  }
  __syncthreads();

  for (int kb = 0; kb < nkb; kb++) {
    int buf = kb & 1;
    bool more = (kb + 1) < nkb;
    if (more) {
      int kof = (kb + 1) * 64;
#pragma unroll
      for (int i = 0; i < 2; i++) {
        int e = t + i * 256;
        areg[i] = *(const short8*)(Aptr + (size_t)(e >> 3) * K + kof + (e & 7) * 8);
      }
#pragma unroll
      for (int i = 0; i < 4; i++) {
        int e = t + i * 256;
        breg[i] = *(const float4*)(Bptr + (size_t)(e >> 4) * K + kof + (e & 15) * 4);
      }
    }
#pragma unroll
    for (int s = 0; s < 4; s++) {
      short8 af = *(const short8*)&As[buf][2 * s + (lane >> 5)][wm * 32 + (lane & 31)][0];
      short8 bf = *(const short8*)&Bs[buf][2 * s + (lane >> 5)][wn * 32 + (lane & 31)][0];
      acc = __builtin_amdgcn_mfma_f32_32x32x16_bf16(af, bf, acc, 0, 0, 0);
    }
    __syncthreads();
    if (more) {
      int nb = 1 - buf;
#pragma unroll
      for (int i = 0; i < 2; i++) {
        int e = t + i * 256;
        *(short8*)&As[nb][e & 7][e >> 3][0] = areg[i];
      }
#pragma unroll
      for (int i = 0; i < 4; i++) {
        int e = t + i * 256;
        short4v v;
        v[0] = (short)f2bf(breg[i].x); v[1] = (short)f2bf(breg[i].y);
        v[2] = (short)f2bf(breg[i].z); v[3] = (short)f2bf(breg[i].w);
        *(short4v*)&Bs[nb][(e & 15) >> 1][e >> 4][((e & 15) & 1) * 4] = v;
      }
      __syncthreads();
    }
  }

  // atomic accumulate: C/D layout col=lane&31, row=(reg&3)+8*(reg>>2)+4*(lane>>5)
  int col = nt * 64 + wn * 32 + (lane & 31);
  int rbase = mt * 64 + wm * 32 + 4 * (lane >> 5);
#pragma unroll
  for (int reg = 0; reg < 16; reg++) {
    int row = rbase + (reg & 3) + 8 * (reg >> 2);
    if (row < Mvalid) atomicAdd(&C[(size_t)row * N + col], acc[reg]);
  }
}

__device__ __forceinline__ float gate_val(const float* sk, int yy, int xx,
                                          float c1w, float c1b, bool use) {
  if (!use) return 1.f;
  float z = sk[yy * HFW + xx] * c1w + c1b;
  return 1.f / (1.f + expf(-z));
}

// ---------------- prep: ROI descriptors (blocks 0..63) + resize taps (64..67) ------
__global__ __launch_bounds__(256) void prep_kernel(
    const float* __restrict__ boxes, const int* __restrict__ group,
    const int* __restrict__ label, const float* __restrict__ skel,
    const float* __restrict__ c1w_, const float* __restrict__ c1b_,
    float* __restrict__ descw, int* __restrict__ desco,
    float* __restrict__ tap4w, int* __restrict__ tap4o,
    float* __restrict__ tap5w, int* __restrict__ tap5o) {
  int blk = blockIdx.x, t = threadIdx.x;
  if (blk < 64) {
    int bg = blk, p = t;
    if (p >= 25) return;
    int b = bg >> 3;
    int i1 = group[bg * 2 + 0], i2 = group[bg * 2 + 1];
    const float* bb1 = boxes + (size_t)(b * 16 + i1) * 4;
    const float* bb2 = boxes + (size_t)(b * 16 + i2) * 4;
    float ux1 = fminf(bb1[0], bb2[0]);
    float uy1 = fminf(bb1[1], bb2[1]);
    float ux2 = fmaxf(bb1[2], bb2[2]);
    float uy2 = fmaxf(bb1[3], bb2[3]);
    float rw = fmaxf(ux2 - ux1, 1.0f), rh = fmaxf(uy2 - uy1, 1.0f);
    int iy = p / 5, ix = p % 5;
    float sy = uy1 + (iy + 0.5f) * (rh * 0.2f);
    float sx = ux1 + (ix + 0.5f) * (rw * 0.2f);
    float valid = (sy >= -1.0f && sy <= 28.0f && sx >= -1.0f && sx <= 28.0f) ? 1.f : 0.f;
    float y = fminf(fmaxf(sy, 0.f), 27.f);
    float x = fminf(fmaxf(sx, 0.f), 27.f);
    int y0 = (int)floorf(y), x0 = (int)floorf(x);
    int y1 = min(y0 + 1, 27), x1 = min(x0 + 1, 27);
    float ly = y - (float)y0, lx = x - (float)x0;
    bool use = (label[bg] != -1);
    float c1w = c1w_[0], c1b = c1b_[0];
    const float* sk = skel + (size_t)bg * NPIX;
    int idx = (bg * 25 + p) * 4;
    descw[idx + 0] = (1.f - ly) * (1.f - lx) * valid * gate_val(sk, y0, x0, c1w, c1b, use);
    descw[idx + 1] = (1.f - ly) * lx * valid * gate_val(sk, y0, x1, c1w, c1b, use);
    descw[idx + 2] = ly * (1.f - lx) * valid * gate_val(sk, y1, x0, c1w, c1b, use);
    descw[idx + 3] = ly * lx * valid * gate_val(sk, y1, x1, c1w, c1b, use);
    desco[idx + 0] = y0 * HFW + x0;
    desco[idx + 1] = y0 * HFW + x1;
    desco[idx + 2] = y1 * HFW + x0;
    desco[idx + 3] = y1 * HFW + x1;
  } else {
    int pix = (blk - 64) * 196 + t;
    if (t >= 196) return;
    int y = pix / HFW, x = pix % HFW;
    {
      float sy = y * (13.0f / 27.0f), sx = x * (13.0f / 27.0f);
      int y0 = (int)sy, x0 = (int)sx;
      int y1 = min(y0 + 1, 13), x1 = min(x0 + 1, 13);
      float ly = sy - y0, lx = sx - x0;
      tap4o[pix * 4 + 0] = y0 * 14 + x0; tap4w[pix * 4 + 0] = (1.f - ly) * (1.f - lx);
      tap4o[pix * 4 + 1] = y0 * 14 + x1; tap4w[pix * 4 + 1] = (1.f - ly) * lx;
      tap4o[pix * 4 + 2] = y1 * 14 + x0; tap4w[pix * 4 + 2] = ly * (1.f - lx);
      tap4o[pix * 4 + 3] = y1 * 14 + x1; tap4w[pix * 4 + 3] = ly * lx;
    }
    {
      float sy = y * (6.0f / 27.0f), sx = x * (6.0f / 27.0f);
      int y0 = (int)sy, x0 = (int)sx;
      int y1 = min(y0 + 1, 6), x1 = min(x0 + 1, 6);
      float ly = sy - y0, lx = sx - x0;
      tap5o[pix * 4 + 0] = y0 * 7 + x0; tap5w[pix * 4 + 0] = (1.f - ly) * (1.f - lx);
      tap5o[pix * 4 + 1] = y0 * 7 + x1; tap5w[pix * 4 + 1] = (1.f - ly) * lx;
      tap5o[pix * 4 + 2] = y1 * 7 + x0; tap5w[pix * 4 + 2] = ly * (1.f - lx);
      tap5o[pix * 4 + 3] = y1 * 7 + x1; tap5w[pix * 4 + 3] = ly * lx;
    }
  }
}

// ---------------- fused resize+ROI + LN1 partial stats -----------------------------
// roisP[bg*25+p][c] = sum_{i,j} (wg_i*tapw_ij)*fT[off_ij][c] + (sum_i wg_i)*bias[c]
// also block-reduces sum/sumsq of its 1536 values -> atomicAdd stats[bg*2 +{0,1}]
__global__ __launch_bounds__(256) void roi_kernel(
    const float* __restrict__ f4T, const float* __restrict__ f5T,
    const float* __restrict__ descw, const int* __restrict__ desco,
    const float* __restrict__ tap4w, const int* __restrict__ tap4o,
    const float* __restrict__ tap5w, const int* __restrict__ tap5o,
    const float* __restrict__ b4, const float* __restrict__ b5,
    float* __restrict__ roisP, float* __restrict__ stats) {
  int p = blockIdx.x, bg = blockIdx.y, b = bg >> 3, t = threadIdx.x;
  __shared__ float cw4[16], cw5[16], wgs;
  __shared__ int co4[16], co5[16];
  int di = (bg * 25 + p) * 4;
  if (t < 16) {
    int i = t >> 2, j = t & 3;
    float wg = descw[di + i];
    int pix = desco[di + i];
    cw4[t] = wg * tap4w[pix * 4 + j];
    co4[t] = (b * HW4 + tap4o[pix * 4 + j]) * 512;
    cw5[t] = wg * tap5w[pix * 4 + j];
    co5[t] = (b * HW5 + tap5o[pix * 4 + j]) * 1024;
  }
  if (t == 16) wgs = descw[di] + descw[di + 1] + descw[di + 2] + descw[di + 3];
  __syncthreads();
  float w4r[16], w5r[16];
  int o4r[16], o5r[16];
  float wg = wgs;
#pragma unroll
  for (int i = 0; i < 16; i++) {
    w4r[i] = cw4[i]; o4r[i] = co4[i];
    w5r[i] = cw5[i]; o5r[i] = co5[i];
  }
  float ls = 0.f, ls2 = 0.f;
  float* outp = roisP + (size_t)(bg * 25 + p) * CAPP;
  for (int c = t; c < 512; c += 256) {
    float acc = wg * b4[c];
#pragma unroll
    for (int i = 0; i < 16; i++) acc = fmaf(w4r[i], f4T[o4r[i] + c], acc);
    outp[c] = acc;
    ls += acc; ls2 = fmaf(acc, acc, ls2);
  }
  for (int c = t; c < 1024; c += 256) {
    float acc = wg * b5[c];
#pragma unroll
    for (int i = 0; i < 16; i++) acc = fmaf(w5r[i], f5T[o5r[i] + c], acc);
    outp[512 + c] = acc;
    ls += acc; ls2 = fmaf(acc, acc, ls2);
  }
  // block reduce -> 2 atomics
  for (int off = 32; off; off >>= 1) {
    ls += __shfl_down(ls, off);
    ls2 += __shfl_down(ls2, off);
  }
  __shared__ float red[8];
  int wv = t >> 6;
  if ((t & 63) == 0) { red[wv] = ls; red[4 + wv] = ls2; }
  __syncthreads();
  if (t == 0) {
    atomicAdd(&stats[bg * 2 + 0], red[0] + red[1] + red[2] + red[3]);
    atomicAdd(&stats[bg * 2 + 1], red[4] + red[5] + red[6] + red[7]);
  }
}

// ---------------- LN1 apply + ReLU -> sknT bf16 [r][k] (k-contig for MFMA A) -------
__global__ __launch_bounds__(256) void ln1b_kernel(
    const float* __restrict__ roisP, const float* __restrict__ stats,
    const float* __restrict__ n1w, const float* __restrict__ n1b,
    unsigned short* __restrict__ sknT) {
  int o = blockIdx.x * 256 + threadIdx.x;  // 64*38400 exactly
  int r = o / D1;
  int k = o - r * D1;
  unsigned c = (unsigned)k / 25u;
  unsigned p = (unsigned)k - c * 25u;
  float x = roisP[((size_t)(r * 25 + p)) * CAPP + c];
  float S = stats[r * 2], S2 = stats[r * 2 + 1];
  float mu = S * (1.f / D1);
  float var = S2 * (1.f / D1) - mu * mu;
  float rs = rsqrtf(var + 1e-5f);
  float v = fmaf((x - mu) * rs, n1w[k], n1b[k]);
  sknT[o] = f2bf(fmaxf(v, 0.f));
}

// ---------------- LN2 + fc2 fused (out1 is [64 r][512 j] row-major) ----------------
__global__ __launch_bounds__(256) void ln2fc2_kernel(
    const float* __restrict__ out1, const float* __restrict__ b1,
    const float* __restrict__ n2w, const float* __restrict__ n2b,
    const float* __restrict__ w2, const float* __restrict__ b2,
    float* __restrict__ out) {
  int r = blockIdx.x, t = threadIdx.x;
  int j1 = t, j2 = t + 256;
  float v1 = out1[r * 512 + j1] + b1[j1];
  float v2 = out1[r * 512 + j2] + b1[j2];
  float s = v1 + v2, s2 = v1 * v1 + v2 * v2;
  for (int off = 32; off; off >>= 1) {
    s += __shfl_down(s, off);
    s2 += __shfl_down(s2, off);
  }
  __shared__ float red[8];
  int wv = t >> 6;
  if ((t & 63) == 0) { red[wv] = s; red[4 + wv] = s2; }
  __syncthreads();
  float S = red[0] + red[1] + red[2] + red[3];
  float S2 = red[4] + red[5] + red[6] + red[7];
  float mu = S / 512.f;
  float var = S2 / 512.f - mu * mu;
  float rs = rsqrtf(var + 1e-5f);
  float n1v = fmaf((v1 - mu) * rs, n2w[j1], n2b[j1]);
  float n2v = fmaf((v2 - mu) * rs, n2w[j2], n2b[j2]);
  float pm[6];
#pragma unroll
  for (int m = 0; m < 6; m++)
    pm[m] = n1v * w2[m * 512 + j1] + n2v * w2[m * 512 + j2];
#pragma unroll
  for (int m = 0; m < 6; m++)
    for (int off = 32; off; off >>= 1) pm[m] += __shfl_down(pm[m], off);
  __shared__ float red2[24];
  if ((t & 63) == 0) {
#pragma unroll
    for (int m = 0; m < 6; m++) red2[wv * 6 + m] = pm[m];
  }
  __syncthreads();
  if (t < 6)
    out[r * 6 + t] = red2[t] + red2[6 + t] + red2[12 + t] + red2[18 + t] + b2[t];
}

extern "C" void kernel_launch(void* const* d_in, const int* in_sizes, int n_in,
                              void* d_out, int out_size, void* d_ws, size_t ws_size,
                              hipStream_t stream) {
  const float* x4    = (const float*)d_in[0];
  const float* x5    = (const float*)d_in[1];
  const float* boxes = (const float*)d_in[2];
  const float* skel  = (const float*)d_in[3];
  const int*   group = (const int*)d_in[4];
  const int*   label = (const int*)d_in[6];
  const float* c1w   = (const float*)d_in[7];
  const float* c1b   = (const float*)d_in[8];
  const float* w2c   = (const float*)d_in[9];
  const float* b2c   = (const float*)d_in[10];
  const float* w3c   = (const float*)d_in[11];
  const float* b3c   = (const float*)d_in[12];
  const float* n1w   = (const float*)d_in[13];
  const float* n1b   = (const float*)d_in[14];
  const float* n2w   = (const float*)d_in[15];
  const float* n2b   = (const float*)d_in[16];
  const float* fw1   = (const float*)d_in[17];
  const float* fb1   = (const float*)d_in[18];
  const float* fw2   = (const float*)d_in[19];
  const float* fb2   = (const float*)d_in[20];
  float* out = (float*)d_out;

  // workspace layout — ALL offsets in FLOAT units.
  float* ws = (float*)d_ws;
  unsigned short* x4T = (unsigned short*)ws;              // 1600*1024 sh = 819200 f
  unsigned short* x5T = (unsigned short*)(ws + 819200);   // 448*2048 sh  = 458752 f
  float* f4T   = ws + 1277952;             // 1600*512  = 819,200 (1568 valid rows)
  float* f5T   = ws + 2097152;             // 448*1024  = 458,752 (392 valid rows)
  float* tap4w = ws + 2555904;             // 3136
  int*   tap4o = (int*)(ws + 2559040);     // 3136
  float* tap5w = ws + 2562176;             // 3136
  int*   tap5o = (int*)(ws + 2565312);     // 3136
  float* descw = ws + 2568448;             // 6400
  int*   desco = (int*)(ws + 2574848);     // 6400
  float* roisP = ws + 2581248;             // 64*25*1536 = 2,457,600
  float* stats = ws + 5038848;             // 128 (raw S, S2 per row)
  unsigned short* sknT = (unsigned short*)(ws + 5038976); // 64*38400 sh = 1,228,800 f
  float* out1  = ws + 6267776;             // 64*512 = 32,768  (end 6,300,544 f = 25.2 MB)

  // zero the atomic accumulators
  hipMemsetAsync(f4T, 0, 819200 * sizeof(float), stream);
  hipMemsetAsync(f5T, 0, 458752 * sizeof(float), stream);
  hipMemsetAsync(stats, 0, 128 * sizeof(float), stream);
  hipMemsetAsync(out1, 0, 32768 * sizeof(float), stream);

  tt_kernel<<<384, 256, 0, stream>>>(x4, x5, x4T, x5T);
  prep_kernel<<<68, 256, 0, stream>>>(boxes, group, label, skel, c1w, c1b,
                                      descw, desco, tap4w, tap4o, tap5w, tap5o);
  // conv4: M=1568 (25 mtiles), N=512 (8 ntiles), K=1024, split 4 x kchunk 256 -> 800 blocks
  gemm_kernel<<<800, 256, 0, stream>>>(x4T, w2c, f4T, 25, 8, 1568, 512, 1024, 256);
  // conv5: M=392 (7 mtiles), N=1024 (16 ntiles), K=2048, split 8 x kchunk 256 -> 896 blocks
  gemm_kernel<<<896, 256, 0, stream>>>(x5T, w3c, f5T, 7, 16, 392, 1024, 2048, 256);
  roi_kernel<<<dim3(25, NR), 256, 0, stream>>>(f4T, f5T, descw, desco,
                                               tap4w, tap4o, tap5w, tap5o,
                                               b2c, b3c, roisP, stats);
  ln1b_kernel<<<9600, 256, 0, stream>>>(roisP, stats, n1w, n1b, sknT);
  // fc1: M=64 (1 mtile), N=512 (8 ntiles), K=38400, split 150 x kchunk 256 -> 1200 blocks
  gemm_kernel<<<1200, 256, 0, stream>>>(sknT, fw1, out1, 1, 8, 64, 512, 38400, 256);
  ln2fc2_kernel<<<NR, 256, 0, stream>>>(out1, fb1, n2w, n2b, fw2, fb2, out);
}